// Round 4
// baseline (1058.659 us; speedup 1.0000x reference)
//
#include <hip/hip_runtime.h>

#define NTOTAL 100000
#define NNODES 16384
#define K 32
#define S 16
#define D 190
#define E 64
#define NREL 3
#define NP (NREL * K)          // 96 gathered rows per node
#define RPW 24                 // rows per wave

// ---------- helper: inverse L2 norms of all feature rows ----------
__global__ __launch_bounds__(256) void norms_kernel(const float* __restrict__ features,
                                                    float* __restrict__ invn) {
    const int row  = blockIdx.x * 4 + (threadIdx.x >> 6);
    const int lane = threadIdx.x & 63;
    if (row >= NTOTAL) return;
    const float2* rp = (const float2*)(features + (size_t)row * D);
    float2 a = rp[lane];
    float ss = fmaf(a.x, a.x, a.y * a.y);
    if (lane < 31) {
        float2 b = rp[64 + lane];
        ss = fmaf(b.x, b.x, fmaf(b.y, b.y, ss));
    }
    #pragma unroll
    for (int off = 32; off; off >>= 1) ss += __shfl_xor(ss, off, 64);
    if (lane == 0) invn[row] = 1.0f / sqrtf(ss);
}

// ---------- fused main kernel: one block per node, rows live in registers ----------
// Row layout across a wave: lane l holds dims {2l, 2l+1} (lo float2) and
// dims {128+2l, 128+2l+1} for l<31 (hi float2). Hi loads for l>=31 are
// clamped in-bounds and their contribution masked via zeroed center-hi.
template <bool HAVE_NORMS>
__global__ __launch_bounds__(256) void interagg_fused(
    const float* __restrict__ features,   // [N_TOTAL, D]
    const int*   __restrict__ nodes,      // [N]
    const int*   __restrict__ neigh1,     // [N, K]
    const int*   __restrict__ neigh2,
    const int*   __restrict__ neigh3,
    const float* __restrict__ weight,     // [D, E]
    const float* __restrict__ avec,       // [2E]
    const float* __restrict__ invn,       // [N_TOTAL] or nullptr
    float*       __restrict__ out)        // [N, E]
{
    __shared__ __align__(16) float s_center[192];
    __shared__ float s_part[8 * 192];     // per-(wave,slot) mean partials, 6 KB
    __shared__ float s_rmean[NREL][192];
    __shared__ float s_sim[NP];
    __shared__ float s_self[NP];          // 1.0 if selected (top-S), else 0.0
    __shared__ int   s_idx[NP];
    __shared__ float s_h[4][E];
    __shared__ float s_dots[4];

    const int n    = blockIdx.x;
    const int t    = threadIdx.x;
    const int lane = t & 63;
    const int wave = t >> 6;

    // ---- phase 1: neighbor indices -> LDS; center row -> registers (+LDS copy) ----
    if (t < NP) {
        const int rel = t >> 5, k = t & 31;
        const int* np = (rel == 0) ? neigh1 : (rel == 1) ? neigh2 : neigh3;
        s_idx[t] = np[n * K + k];
    }
    const int crow = nodes[n];
    const int hidx = (lane < 31) ? (64 + lane) : 94;   // clamped in-bounds
    const float2* crp = (const float2*)(features + (size_t)crow * D);
    float2 c0 = crp[lane];
    float2 c1 = crp[hidx];
    if (lane >= 31) { c1.x = 0.f; c1.y = 0.f; }        // dims >=190 don't exist
    if (wave == 0) {
        ((float2*)s_center)[lane] = c0;
        if (lane < 31) ((float2*)s_center)[64 + lane] = c1;
    }
    __syncthreads();

    // ---- phase 2: 48-load burst (24 rows stay in VGPRs), dots, butterflies ----
    const int pbase = wave * RPW;
    float2 va[RPW], vb[RPW];
    float  dotv[RPW];
    float  iv[RPW];                        // uniform -> SGPRs via s_load
    #pragma unroll
    for (int i = 0; i < RPW; ++i) {
        const int rid = __builtin_amdgcn_readfirstlane(s_idx[pbase + i]);
        const float2* rp = (const float2*)(features + (size_t)rid * D);
        va[i] = rp[lane];
        vb[i] = rp[hidx];
        if (HAVE_NORMS) iv[i] = invn[rid];
    }
    #pragma unroll
    for (int i = 0; i < RPW; ++i) {
        dotv[i] = fmaf(c0.x, va[i].x, fmaf(c0.y, va[i].y,
                  fmaf(c1.x, vb[i].x, c1.y * vb[i].y)));
    }
    #pragma unroll
    for (int i = 0; i < RPW; ++i) {
        float v = dotv[i];
        #pragma unroll
        for (int off = 32; off; off >>= 1) v += __shfl_xor(v, off, 64);
        dotv[i] = v;
    }
    if (HAVE_NORMS) {
        if (lane == 0) {
            #pragma unroll
            for (int i = 0; i < RPW; ++i) s_sim[pbase + i] = dotv[i] * iv[i];
        }
    } else {
        float ssv[RPW];
        #pragma unroll
        for (int i = 0; i < RPW; ++i) {
            float2 vm = vb[i];
            if (lane >= 31) { vm.x = 0.f; vm.y = 0.f; }
            float s2 = fmaf(va[i].x, va[i].x, fmaf(va[i].y, va[i].y,
                       fmaf(vm.x, vm.x, vm.y * vm.y)));
            #pragma unroll
            for (int off = 32; off; off >>= 1) s2 += __shfl_xor(s2, off, 64);
            ssv[i] = s2;
        }
        if (lane == 0) {
            #pragma unroll
            for (int i = 0; i < RPW; ++i) s_sim[pbase + i] = dotv[i] / sqrtf(ssv[i]);
        }
    }
    __syncthreads();

    // ---- phase 3a: top-S by rank within each relation (ties -> lower index) ----
    if (t < NP) {
        const float sk = s_sim[t];
        const int base = t & ~31;
        int rank = 0;
        #pragma unroll
        for (int j = 0; j < K; ++j) {
            const float sj = s_sim[base + j];
            rank += (sj > sk) || (sj == sk && (base + j) < t);
        }
        s_self[t] = (rank < S) ? 1.0f : 0.0f;
    }
    __syncthreads();

    // ---- phase 3b: masked mean from REGISTERS (no re-fetch), per-wave partials ----
    {
        const int firstrel = pbase >> 5;
        float2 a0l = {0.f, 0.f}, a0h = {0.f, 0.f};
        float2 a1l = {0.f, 0.f}, a1h = {0.f, 0.f};
        #pragma unroll
        for (int i = 0; i < RPW; ++i) {
            const int p = pbase + i;
            const float f  = s_self[p];                 // uniform LDS broadcast
            const float m0 = ((p >> 5) == firstrel) ? f : 0.f;
            const float m1 = f - m0;
            a0l.x = fmaf(m0, va[i].x, a0l.x); a0l.y = fmaf(m0, va[i].y, a0l.y);
            a0h.x = fmaf(m0, vb[i].x, a0h.x); a0h.y = fmaf(m0, vb[i].y, a0h.y);
            a1l.x = fmaf(m1, va[i].x, a1l.x); a1l.y = fmaf(m1, va[i].y, a1l.y);
            a1h.x = fmaf(m1, vb[i].x, a1h.x); a1h.y = fmaf(m1, vb[i].y, a1h.y);
        }
        float2* P0 = (float2*)(s_part + (wave * 2 + 0) * 192);
        float2* P1 = (float2*)(s_part + (wave * 2 + 1) * 192);
        P0[lane] = a0l;
        if (lane < 31) P0[64 + lane] = a0h;             // lanes>=31 hold garbage hi; never stored
        if (wave == 1 || wave == 2) {                   // only waves 1,2 span two relations
            P1[lane] = a1l;
            if (lane < 31) P1[64 + lane] = a1h;
        }
    }
    __syncthreads();

    // ---- phase 3c: reduce partials -> s_rmean (+ /16 + relu) ----
    // rel0 = w0s0 + w1s0 ; rel1 = w1s1 + w2s0 ; rel2 = w2s1 + w3s0
    if (t < 192) {
        const float q0 = s_part[0 * 192 + t] + s_part[2 * 192 + t];
        const float q1 = s_part[3 * 192 + t] + s_part[4 * 192 + t];
        const float q2 = s_part[5 * 192 + t] + s_part[6 * 192 + t];
        s_rmean[0][t] = fmaxf(q0 * (1.f / S), 0.f);
        s_rmean[1][t] = fmaxf(q1 * (1.f / S), 0.f);
        s_rmean[2][t] = fmaxf(q2 * (1.f / S), 0.f);
    }
    __syncthreads();

    // ---- phase 4: h[v] = vec_v @ W (wave 0: center, waves 1-3: relations) ----
    {
        const float* vec = (wave == 0) ? s_center : s_rmean[wave - 1];
        float a0 = 0.f, a1 = 0.f;
        #pragma unroll 2
        for (int d = 0; d < D; d += 2) {
            a0 = fmaf(vec[d],     weight[d * E + lane],       a0);
            a1 = fmaf(vec[d + 1], weight[(d + 1) * E + lane], a1);
        }
        s_h[wave][lane] = a0 + a1;
    }
    __syncthreads();

    // ---- phase 5: attention dots ----
    {
        const float* av = (wave == 0) ? avec : (avec + E);
        float val = s_h[wave][lane] * av[lane];
        #pragma unroll
        for (int off = 32; off; off >>= 1) val += __shfl_xor(val, off, 64);
        if (lane == 0) s_dots[wave] = val;
    }
    __syncthreads();

    // ---- phase 6: leaky-relu, 3-way softmax, aggregate, relu, store ----
    if (t < E) {
        const float d0 = s_dots[0];
        float e1 = d0 + s_dots[1];
        float e2 = d0 + s_dots[2];
        float e3 = d0 + s_dots[3];
        e1 = (e1 >= 0.f) ? e1 : 0.2f * e1;
        e2 = (e2 >= 0.f) ? e2 : 0.2f * e2;
        e3 = (e3 >= 0.f) ? e3 : 0.2f * e3;
        const float m  = fmaxf(e1, fmaxf(e2, e3));
        const float x1 = expf(e1 - m), x2 = expf(e2 - m), x3 = expf(e3 - m);
        const float inv = 1.f / (x1 + x2 + x3);
        const float agg = (x1 * s_h[1][t] + x2 * s_h[2][t] + x3 * s_h[3][t]) * inv;
        out[(size_t)n * E + t] = fmaxf(s_h[0][t] + agg, 0.f);
    }
}

extern "C" void kernel_launch(void* const* d_in, const int* in_sizes, int n_in,
                              void* d_out, int out_size, void* d_ws, size_t ws_size,
                              hipStream_t stream) {
    const float* features = (const float*)d_in[0];
    const int*   nodes    = (const int*)  d_in[1];
    const int*   neigh1   = (const int*)  d_in[2];
    const int*   neigh2   = (const int*)  d_in[3];
    const int*   neigh3   = (const int*)  d_in[4];
    const float* weight   = (const float*)d_in[5];
    const float* avec     = (const float*)d_in[6];
    float*       out      = (float*)d_out;

    const bool have_norms = ws_size >= (size_t)NTOTAL * sizeof(float);
    if (have_norms) {
        float* invn = (float*)d_ws;
        norms_kernel<<<(NTOTAL + 3) / 4, 256, 0, stream>>>(features, invn);
        interagg_fused<true><<<NNODES, 256, 0, stream>>>(
            features, nodes, neigh1, neigh2, neigh3, weight, avec, invn, out);
    } else {
        interagg_fused<false><<<NNODES, 256, 0, stream>>>(
            features, nodes, neigh1, neigh2, neigh3, weight, avec, nullptr, out);
    }
}

// Round 5
// 439.654 us; speedup vs baseline: 2.4079x; 2.4079x over previous
//
#include <hip/hip_runtime.h>

#define NTOTAL 100000
#define NNODES 16384
#define K 32
#define S 16
#define D 190
#define E 64
#define NREL 3

__device__ float g_invn[NTOTAL];
__device__ float g_wa[384];    // [0..191] = W@a1, [192..383] = W@a2 (dims 190,191 zeroed)

// ---------- inverse L2 norms of all feature rows ----------
__global__ __launch_bounds__(256) void norms_kernel(const float* __restrict__ features) {
    const int row  = blockIdx.x * 4 + (threadIdx.x >> 6);
    const int lane = threadIdx.x & 63;
    if (row >= NTOTAL) return;
    const float2* rp = (const float2*)(features + (size_t)row * D);
    float2 a = rp[lane];
    float ss = fmaf(a.x, a.x, a.y * a.y);
    if (lane < 31) {
        float2 b = rp[64 + lane];
        ss = fmaf(b.x, b.x, fmaf(b.y, b.y, ss));
    }
    #pragma unroll
    for (int off = 32; off; off >>= 1) ss += __shfl_xor(ss, off, 64);
    if (lane == 0) g_invn[row] = 1.0f / sqrtf(ss);
}

// ---------- wa1 = W@a1, wa2 = W@a2 ----------
__global__ __launch_bounds__(192) void prep_wa(const float* __restrict__ weight,
                                               const float* __restrict__ avec) {
    const int d = threadIdx.x;              // 0..191
    float s1 = 0.f, s2 = 0.f;
    if (d < D) {
        const float* wr = weight + d * E;
        #pragma unroll 8
        for (int e = 0; e < E; ++e) {
            const float w = wr[e];
            s1 = fmaf(w, avec[e],     s1);
            s2 = fmaf(w, avec[E + e], s2);
        }
    }
    g_wa[d]       = s1;
    g_wa[192 + d] = s2;
}

// ---------- main: one WAVE per node, no __syncthreads ----------
// Lane data layout for a 190-float row: lo = dims {2l, 2l+1} (float2),
// hi = dims {128+2l, 129+2l} for l<31 (float2, clamped loads for l>=31,
// masked by zeroing the OTHER operand of every product).
__global__ __launch_bounds__(256, 4) void interagg_wave(
    const float* __restrict__ features,   // [N_TOTAL, D]
    const int*   __restrict__ nodes,      // [N]
    const int*   __restrict__ neigh1,     // [N, K]
    const int*   __restrict__ neigh2,
    const int*   __restrict__ neigh3,
    const float* __restrict__ weight,     // [D, E]
    float*       __restrict__ out)        // [N, E]
{
    __shared__ int   s_idx[4][96];
    __shared__ float s_sim[4][32];
    __shared__ __align__(16) float s_v[4][192];

    const int t    = threadIdx.x;
    const int lane = t & 63;
    const int wave = t >> 6;
    const int n    = blockIdx.x * 4 + wave;

    int*   idxw = s_idx[wave];
    float* simw = s_sim[wave];
    float* vw   = s_v[wave];

    // ---- indices -> per-wave LDS (2 coalesced loads) ----
    {
        const int v1 = (lane < 32) ? neigh1[n * K + lane] : neigh2[n * K + (lane - 32)];
        idxw[lane] = v1;
        if (lane < 32) idxw[64 + lane] = neigh3[n * K + lane];
    }

    // ---- center row -> registers ----
    const int  crow = nodes[n];
    const int  hl   = (lane < 31) ? lane : 30;     // clamped hi index (dims <=189)
    const bool hiok = (lane < 31);
    const float2* crp = (const float2*)(features + (size_t)crow * D);
    float2 c0 = crp[lane];
    float2 c1 = crp[64 + hl];
    if (!hiok) { c1.x = 0.f; c1.y = 0.f; }

    float rlx[NREL], rly[NREL], rhx[NREL], rhy[NREL];   // relu'd means (static idx)

    #pragma unroll
    for (int rel = 0; rel < NREL; ++rel) {
        const int* idz = idxw + rel * 32;

        // ---- sims: 4 bursts of 8 rows ----
        #pragma unroll
        for (int b = 0; b < 4; ++b) {
            float2 va[8], vb[8];
            float  iv[8];
            #pragma unroll
            for (int i = 0; i < 8; ++i) {
                const int rid = idz[b * 8 + i];            // uniform ds_read
                const float2* rp = (const float2*)(features + (size_t)rid * D);
                va[i] = rp[lane];
                vb[i] = rp[64 + hl];
                iv[i] = g_invn[rid];
            }
            float dt[8];
            #pragma unroll
            for (int i = 0; i < 8; ++i)
                dt[i] = fmaf(c0.x, va[i].x, fmaf(c0.y, va[i].y,
                        fmaf(c1.x, vb[i].x, c1.y * vb[i].y)));
            #pragma unroll
            for (int off = 32; off; off >>= 1) {
                #pragma unroll
                for (int i = 0; i < 8; ++i)
                    dt[i] += __shfl_xor(dt[i], off, 64);
            }
            if (lane == 0) {
                #pragma unroll
                for (int i = 0; i < 8; ++i)
                    simw[b * 8 + i] = dt[i] * iv[i];
            }
        }

        // ---- top-S by rank via shuffles (ties -> lower index, as lax.top_k) ----
        const float sk = simw[lane & 31];
        int rank = (lane < 32) ? 0 : 64;
        #pragma unroll
        for (int j = 0; j < K; ++j) {
            const float sj = __shfl(sk, j, 64);
            rank += (sj > sk) || (sj == sk && j < lane);
        }
        const unsigned long long bal = __ballot(rank < S);
        unsigned int m = (unsigned int)bal;               // wave-uniform, 16 bits set

        // ---- mean of 16 selected rows (L1/L2-hot re-gather), 2 bursts of 8 ----
        float2 acc_lo = make_float2(0.f, 0.f);
        float2 acc_hi = make_float2(0.f, 0.f);
        #pragma unroll
        for (int half = 0; half < 2; ++half) {
            float2 ua[8], ub[8];
            #pragma unroll
            for (int i = 0; i < 8; ++i) {
                const int k = __ffs(m) - 1; m &= m - 1;
                const int rid = idz[k];
                const float2* rp = (const float2*)(features + (size_t)rid * D);
                ua[i] = rp[lane];
                ub[i] = rp[64 + hl];
            }
            #pragma unroll
            for (int i = 0; i < 8; ++i) {
                acc_lo.x += ua[i].x; acc_lo.y += ua[i].y;
                acc_hi.x += ub[i].x; acc_hi.y += ub[i].y;
            }
        }
        rlx[rel] = fmaxf(acc_lo.x * (1.f / S), 0.f);
        rly[rel] = fmaxf(acc_lo.y * (1.f / S), 0.f);
        rhx[rel] = fmaxf(acc_hi.x * (1.f / S), 0.f);      // garbage for !hiok, masked below
        rhy[rel] = fmaxf(acc_hi.y * (1.f / S), 0.f);
    }

    // ---- attention scores: e_r = center.wa1 + rmean_r.wa2 (4 interleaved reduces) ----
    float2 w1l = ((const float2*)g_wa)[lane];
    float2 w1h = ((const float2*)g_wa)[64 + hl];
    float2 w2l = ((const float2*)(g_wa + 192))[lane];
    float2 w2h = ((const float2*)(g_wa + 192))[64 + hl];
    if (!hiok) { w1h.x = w1h.y = 0.f; w2h.x = w2h.y = 0.f; }

    float dv[4];
    dv[0] = fmaf(c0.x, w1l.x, fmaf(c0.y, w1l.y, fmaf(c1.x, w1h.x, c1.y * w1h.y)));
    #pragma unroll
    for (int r = 0; r < NREL; ++r)
        dv[1 + r] = fmaf(rlx[r], w2l.x, fmaf(rly[r], w2l.y,
                    fmaf(rhx[r], w2h.x, rhy[r] * w2h.y)));
    #pragma unroll
    for (int off = 32; off; off >>= 1) {
        #pragma unroll
        for (int i = 0; i < 4; ++i)
            dv[i] += __shfl_xor(dv[i], off, 64);
    }

    float e1 = dv[0] + dv[1], e2 = dv[0] + dv[2], e3 = dv[0] + dv[3];
    e1 = (e1 >= 0.f) ? e1 : 0.2f * e1;
    e2 = (e2 >= 0.f) ? e2 : 0.2f * e2;
    e3 = (e3 >= 0.f) ? e3 : 0.2f * e3;
    const float mx  = fmaxf(e1, fmaxf(e2, e3));
    const float x1 = expf(e1 - mx), x2 = expf(e2 - mx), x3 = expf(e3 - mx);
    const float inv = 1.f / (x1 + x2 + x3);
    const float a1w = x1 * inv, a2w = x2 * inv, a3w = x3 * inv;

    // ---- v = center + sum att_r * rmean_r ; out = relu(v @ W) (ONE matvec) ----
    float2 v_lo, v_hi;
    v_lo.x = fmaf(a1w, rlx[0], fmaf(a2w, rlx[1], fmaf(a3w, rlx[2], c0.x)));
    v_lo.y = fmaf(a1w, rly[0], fmaf(a2w, rly[1], fmaf(a3w, rly[2], c0.y)));
    v_hi.x = fmaf(a1w, rhx[0], fmaf(a2w, rhx[1], fmaf(a3w, rhx[2], c1.x)));
    v_hi.y = fmaf(a1w, rhy[0], fmaf(a2w, rhy[1], fmaf(a3w, rhy[2], c1.y)));

    ((float2*)vw)[lane] = v_lo;
    if (hiok) ((float2*)vw)[64 + lane] = v_hi;            // dims 190,191 never read

    float acc = 0.f;
    const float* wcol = weight + lane;
    #pragma unroll 4
    for (int d4 = 0; d4 < 47; ++d4) {                     // dims 0..187
        const float4 vv = *((const float4*)vw + d4);      // uniform b128 broadcast
        const int d = d4 * 4;
        acc = fmaf(vv.x, wcol[(d    ) * E], acc);
        acc = fmaf(vv.y, wcol[(d + 1) * E], acc);
        acc = fmaf(vv.z, wcol[(d + 2) * E], acc);
        acc = fmaf(vv.w, wcol[(d + 3) * E], acc);
    }
    {                                                     // dims 188,189
        const float2 vv2 = *((const float2*)vw + 94);
        acc = fmaf(vv2.x, wcol[188 * E], acc);
        acc = fmaf(vv2.y, wcol[189 * E], acc);
    }
    out[(size_t)n * E + lane] = fmaxf(acc, 0.f);
}

extern "C" void kernel_launch(void* const* d_in, const int* in_sizes, int n_in,
                              void* d_out, int out_size, void* d_ws, size_t ws_size,
                              hipStream_t stream) {
    const float* features = (const float*)d_in[0];
    const int*   nodes    = (const int*)  d_in[1];
    const int*   neigh1   = (const int*)  d_in[2];
    const int*   neigh2   = (const int*)  d_in[3];
    const int*   neigh3   = (const int*)  d_in[4];
    const float* weight   = (const float*)d_in[5];
    const float* avec     = (const float*)d_in[6];
    float*       out      = (float*)d_out;

    norms_kernel<<<NTOTAL / 4, 256, 0, stream>>>(features);
    prep_wa<<<1, 192, 0, stream>>>(weight, avec);
    interagg_wave<<<NNODES / 4, 256, 0, stream>>>(
        features, nodes, neigh1, neigh2, neigh3, weight, out);
}